// Round 1
// baseline (1949.590 us; speedup 1.0000x reference)
//
#include <hip/hip_runtime.h>

#define B_    4
#define C_    64
#define H_    160
#define W_    160
#define O_    64
#define G_    4
#define K_    9
#define CG_   16      // channels per group
#define MODC_ 36      // G_*K_
#define OFFC_ 72      // 2*G_*K_
#define HW_   (H_*W_)

__device__ __forceinline__ float sigmoidf(float v) {
    return 1.0f / (1.0f + __expf(-v));
}

// w_reg (O,C,3,3) -> wt[((g*K + k)*CG + c)*O + o]  (o contiguous for scalar loads)
__global__ __launch_bounds__(256) void k_transpose(const float* __restrict__ w,
                                                   float* __restrict__ wt) {
    int i = blockIdx.x * 256 + threadIdx.x;
    if (i >= O_ * C_ * K_) return;
    int k  = i % K_;
    int t  = i / K_;
    int ch = t % C_;
    int o  = t / C_;
    int g  = ch >> 4;
    int c  = ch & 15;
    wt[((g * K_ + k) * CG_ + c) * O_ + o] = w[i];
}

// off = 80*sigmoid(offset_map) - 40   (vectorized, exact grid coverage)
__global__ __launch_bounds__(256) void k_offsets(const float* __restrict__ om,
                                                 float* __restrict__ off) {
    int i = blockIdx.x * 256 + threadIdx.x;
    float4 v = ((const float4*)om)[i];
    float4 r;
    r.x = 80.0f * sigmoidf(v.x) - 40.0f;
    r.y = 80.0f * sigmoidf(v.y) - 40.0f;
    r.z = 80.0f * sigmoidf(v.z) - 40.0f;
    r.w = 80.0f * sigmoidf(v.w) - 40.0f;
    ((float4*)off)[i] = r;
}

// modulator = 2*sigmoid(conv3x3(warp_ref, w_mod) + b_mod)
// one thread = one pixel x 18 output channels; blockIdx.x&1 selects channel half
__global__ __launch_bounds__(256) void k_mod(const float* __restrict__ x,
                                             const float* __restrict__ wm,
                                             const float* __restrict__ bm,
                                             float* __restrict__ mod) {
    int pix   = (blockIdx.x >> 1) * 256 + threadIdx.x;
    int jbase = (blockIdx.x & 1) * 18;
    int b   = pix / HW_;
    int rem = pix - b * HW_;
    int y   = rem / W_;
    int xx  = rem - y * W_;

    int   cy[3], cx[3];
    float my[3], mx[3];
#pragma unroll
    for (int d = 0; d < 3; ++d) {
        int yy = y + d - 1;
        my[d] = ((unsigned)yy < (unsigned)H_) ? 1.0f : 0.0f;
        cy[d] = min(max(yy, 0), H_ - 1);
        int xv = xx + d - 1;
        mx[d] = ((unsigned)xv < (unsigned)W_) ? 1.0f : 0.0f;
        cx[d] = min(max(xv, 0), W_ - 1);
    }

    float acc[18];
#pragma unroll
    for (int j = 0; j < 18; ++j) acc[j] = bm[jbase + j];

    const float* xb = x + b * C_ * HW_;
    for (int c = 0; c < C_; ++c) {
        const float* xc = xb + c * HW_;
        float v[9];
#pragma unroll
        for (int dy = 0; dy < 3; ++dy)
#pragma unroll
            for (int dx = 0; dx < 3; ++dx)
                v[dy * 3 + dx] = xc[cy[dy] * W_ + cx[dx]] * (my[dy] * mx[dx]);

        const float* wc = wm + (jbase * C_ + c) * K_;
#pragma unroll
        for (int j = 0; j < 18; ++j) {
            const float* wj = wc + j * C_ * K_;
#pragma unroll
            for (int t = 0; t < 9; ++t)
                acc[j] = fmaf(wj[t], v[t], acc[j]);
        }
    }

    float* mp = mod + (size_t)(b * MODC_ + jbase) * HW_ + rem;
#pragma unroll
    for (int j = 0; j < 18; ++j)
        mp[j * HW_] = 2.0f * sigmoidf(acc[j]);
}

// deformable conv main: one thread = one pixel x 32 output channels
__global__ __launch_bounds__(256) void k_deform(const float* __restrict__ x,
                                                const float* __restrict__ off,
                                                const float* __restrict__ mod,
                                                const float* __restrict__ wt,
                                                float* __restrict__ out) {
    int pix   = (blockIdx.x >> 1) * 256 + threadIdx.x;
    int obase = (blockIdx.x & 1) * 32;
    int b   = pix / HW_;
    int rem = pix - b * HW_;
    int y   = rem / W_;
    int xx  = rem - y * W_;

    float acc[32];
#pragma unroll
    for (int o = 0; o < 32; ++o) acc[o] = 0.0f;

    const float* xb   = x + b * C_ * HW_;
    const float* offp = off + (size_t)b * OFFC_ * HW_ + rem;
    const float* modp = mod + (size_t)b * MODC_ * HW_ + rem;

    for (int g = 0; g < G_; ++g) {
        const float* xg = xb + g * CG_ * HW_;
        for (int k = 0; k < K_; ++k) {
            int ki = k / 3;
            int kj = k - ki * 3;
            float oy = offp[(g * 18 + 2 * k) * HW_];
            float ox = offp[(g * 18 + 2 * k + 1) * HW_];
            float m  = modp[(g * K_ + k) * HW_];

            float py  = oy + (float)(y - 1 + ki);
            float px  = ox + (float)(xx - 1 + kj);
            float y0f = floorf(py), x0f = floorf(px);
            float wy  = py - y0f,   wx  = px - x0f;
            int y0 = (int)y0f, x0i = (int)x0f;
            int y1 = y0 + 1,   x1  = x0i + 1;
            float vy0 = ((unsigned)y0  < (unsigned)H_) ? 1.0f : 0.0f;
            float vy1 = ((unsigned)y1  < (unsigned)H_) ? 1.0f : 0.0f;
            float vx0 = ((unsigned)x0i < (unsigned)W_) ? 1.0f : 0.0f;
            float vx1 = ((unsigned)x1  < (unsigned)W_) ? 1.0f : 0.0f;
            int yc0 = min(max(y0, 0), H_ - 1);
            int yc1 = min(max(y1, 0), H_ - 1);
            int xc0 = min(max(x0i, 0), W_ - 1);
            int xc1 = min(max(x1, 0), W_ - 1);

            float w00 = (1.0f - wy) * (1.0f - wx) * vy0 * vx0 * m;
            float w01 = (1.0f - wy) * wx          * vy0 * vx1 * m;
            float w10 = wy          * (1.0f - wx) * vy1 * vx0 * m;
            float w11 = wy          * wx          * vy1 * vx1 * m;

            int i00 = yc0 * W_ + xc0, i01 = yc0 * W_ + xc1;
            int i10 = yc1 * W_ + xc0, i11 = yc1 * W_ + xc1;

            const float* wp = wt + (size_t)((g * K_ + k) * CG_) * O_ + obase;
#pragma unroll
            for (int c = 0; c < CG_; ++c) {
                const float* pc = xg + c * HW_;
                float v = w00 * pc[i00] + w01 * pc[i01] +
                          w10 * pc[i10] + w11 * pc[i11];
                const float* wpc = wp + c * O_;
#pragma unroll
                for (int o = 0; o < 32; ++o)
                    acc[o] = fmaf(wpc[o], v, acc[o]);
            }
        }
    }

    float* op = out + (size_t)b * O_ * HW_ + rem;
#pragma unroll
    for (int o = 0; o < 32; ++o)
        op[(obase + o) * HW_] = acc[o];
}

extern "C" void kernel_launch(void* const* d_in, const int* in_sizes, int n_in,
                              void* d_out, int out_size, void* d_ws, size_t ws_size,
                              hipStream_t stream) {
    const float* warp = (const float*)d_in[0];  // (4,64,160,160)
    const float* omap = (const float*)d_in[1];  // (4,72,160,160)
    const float* wreg = (const float*)d_in[2];  // (64,64,3,3)
    const float* wmod = (const float*)d_in[3];  // (36,64,3,3)
    const float* bmod = (const float*)d_in[4];  // (36,)

    float* out     = (float*)d_out;                       // (4,64,160,160)
    float* out_off = out + (size_t)B_ * O_ * HW_;         // (4,72,160,160)

    float* mod = (float*)d_ws;                            // (4,36,160,160) = 14.75 MB
    float* wt  = mod + (size_t)B_ * MODC_ * HW_;          // 36864 floats

    hipLaunchKernelGGL(k_transpose, dim3((O_ * C_ * K_ + 255) / 256), dim3(256),
                       0, stream, wreg, wt);
    hipLaunchKernelGGL(k_offsets, dim3((B_ * OFFC_ * HW_ / 4) / 256), dim3(256),
                       0, stream, omap, out_off);
    hipLaunchKernelGGL(k_mod, dim3(800), dim3(256), 0, stream,
                       warp, wmod, bmod, mod);
    hipLaunchKernelGGL(k_deform, dim3(800), dim3(256), 0, stream,
                       warp, out_off, mod, wt, out);
}

// Round 2
// 592.197 us; speedup vs baseline: 3.2921x; 3.2921x over previous
//
#include <hip/hip_runtime.h>

#define B_    4
#define C_    64
#define H_    160
#define W_    160
#define O_    64
#define G_    4
#define K_    9
#define CG_   16      // channels per group
#define MODC_ 36      // G_*K_
#define OFFC_ 72      // 2*G_*K_
#define HW_   (H_*W_)

__device__ __forceinline__ float sigmoidf(float v) {
    return 1.0f / (1.0f + __expf(-v));
}

// ---------------------------------------------------------------------------
// warp_ref NCHW -> grouped NHWC: xt[((b*4+g)*HW + pix)*16 + c]
// block = 256 threads, one (b,g, 256-pixel) tile per block; LDS transpose so
// both global read and global write are coalesced (write = 64 B/lane).
// ---------------------------------------------------------------------------
__global__ __launch_bounds__(256) void k_nhwc(const float* __restrict__ x,
                                              float* __restrict__ xt) {
    __shared__ float lds[256][17];
    int bg   = blockIdx.x / 100;           // b*4+g  (16 combos)
    int pix0 = (blockIdx.x % 100) * 256;
    const float* src = x + (size_t)bg * CG_ * HW_ + pix0;
#pragma unroll
    for (int c = 0; c < CG_; ++c)
        lds[threadIdx.x][c] = src[c * HW_ + threadIdx.x];
    __syncthreads();
    float4* dst = (float4*)(xt + ((size_t)bg * HW_ + pix0 + threadIdx.x) * CG_);
#pragma unroll
    for (int q = 0; q < 4; ++q)
        dst[q] = make_float4(lds[threadIdx.x][4 * q + 0],
                             lds[threadIdx.x][4 * q + 1],
                             lds[threadIdx.x][4 * q + 2],
                             lds[threadIdx.x][4 * q + 3]);
}

// ---------------------------------------------------------------------------
// weight transposes:
//  w_reg (O,C,3,3) -> wt_def[((g*9+k)*16 + c)*64 + o]      (36864 floats)
//  w_mod (36,C,3,3)-> wt_mod[((c*9)+t)*36 + j]             (20736 floats)
// ---------------------------------------------------------------------------
__global__ __launch_bounds__(256) void k_wt(const float* __restrict__ wreg,
                                            const float* __restrict__ wmod,
                                            float* __restrict__ wt_def,
                                            float* __restrict__ wt_mod) {
    int i = blockIdx.x * 256 + threadIdx.x;
    if (i < O_ * C_ * K_) {
        int o  = i & 63;
        int r  = i >> 6;
        int c  = r & 15;
        int gk = r >> 4;            // g*9+k
        int g  = gk / 9;
        int k  = gk - g * 9;
        wt_def[i] = wreg[((o * C_) + g * CG_ + c) * K_ + k];
    } else {
        int i2 = i - O_ * C_ * K_;
        if (i2 < MODC_ * C_ * K_) {
            int j = i2 % MODC_;
            int r = i2 / MODC_;
            int t = r % K_;
            int c = r / K_;
            wt_mod[i2] = wmod[((j * C_) + c) * K_ + t];
        }
    }
}

// off = 80*sigmoid(offset_map) - 40
__global__ __launch_bounds__(256) void k_offsets(const float* __restrict__ om,
                                                 float* __restrict__ off) {
    int i = blockIdx.x * 256 + threadIdx.x;
    float4 v = ((const float4*)om)[i];
    float4 r;
    r.x = 80.0f * sigmoidf(v.x) - 40.0f;
    r.y = 80.0f * sigmoidf(v.y) - 40.0f;
    r.z = 80.0f * sigmoidf(v.z) - 40.0f;
    r.w = 80.0f * sigmoidf(v.w) - 40.0f;
    ((float4*)off)[i] = r;
}

// ---------------------------------------------------------------------------
// modulator = 2*sigmoid(conv3x3(warp_ref, w_mod) + b_mod)
// one thread = one pixel, all 36 channels. NHWC input, float4 loads.
// ---------------------------------------------------------------------------
__global__ __launch_bounds__(256) void k_mod(const float* __restrict__ xt,
                                             const float* __restrict__ wt_mod,
                                             const float* __restrict__ bm,
                                             float* __restrict__ mod) {
    int pix = blockIdx.x * 256 + threadIdx.x;
    int b   = pix / HW_;
    int rem = pix - b * HW_;
    int y   = rem / W_;
    int xx  = rem - y * W_;

    int   cy[3], cx[3];
    float my[3], mx[3];
#pragma unroll
    for (int d = 0; d < 3; ++d) {
        int yy = y + d - 1;
        my[d] = ((unsigned)yy < (unsigned)H_) ? 1.0f : 0.0f;
        cy[d] = min(max(yy, 0), H_ - 1);
        int xv = xx + d - 1;
        mx[d] = ((unsigned)xv < (unsigned)W_) ? 1.0f : 0.0f;
        cx[d] = min(max(xv, 0), W_ - 1);
    }

    float acc[MODC_];
#pragma unroll
    for (int j = 0; j < MODC_; ++j) acc[j] = bm[j];

#pragma unroll 1
    for (int g = 0; g < G_; ++g) {
        const float* xg = xt + ((size_t)(b * G_ + g) * HW_) * CG_;
#pragma unroll 1
        for (int t = 0; t < K_; ++t) {
            int dy = t / 3, dx = t - dy * 3;
            float msk = my[dy] * mx[dx];
            const float4* px4 = (const float4*)(xg + (size_t)(cy[dy] * W_ + cx[dx]) * CG_);
#pragma unroll 1
            for (int c4 = 0; c4 < 4; ++c4) {
                float4 v = px4[c4];
                v.x *= msk; v.y *= msk; v.z *= msk; v.w *= msk;
                const float* wp = wt_mod + ((size_t)((g * CG_ + c4 * 4) * K_) + t) * MODC_;
#pragma unroll
                for (int cc = 0; cc < 4; ++cc) {
                    float vs = (cc == 0) ? v.x : (cc == 1) ? v.y : (cc == 2) ? v.z : v.w;
                    const float* w = wp + (size_t)cc * K_ * MODC_;
#pragma unroll
                    for (int j = 0; j < MODC_; ++j)
                        acc[j] = fmaf(w[j], vs, acc[j]);
                }
            }
        }
    }

    float* mp = mod + (size_t)b * MODC_ * HW_ + rem;
#pragma unroll
    for (int j = 0; j < MODC_; ++j)
        mp[(size_t)j * HW_] = 2.0f * sigmoidf(acc[j]);
}

// ---------------------------------------------------------------------------
// deformable conv: one thread = one pixel, ALL 64 output channels.
// NHWC gathers (4x float4 per corner), wave-uniform weights via wt_def.
// ---------------------------------------------------------------------------
__global__ __launch_bounds__(256) void k_deform(const float* __restrict__ xt,
                                                const float* __restrict__ off,
                                                const float* __restrict__ mod,
                                                const float* __restrict__ wt,
                                                float* __restrict__ out) {
    int pix = blockIdx.x * 256 + threadIdx.x;
    int b   = pix / HW_;
    int rem = pix - b * HW_;
    int y   = rem / W_;
    int xx  = rem - y * W_;

    float acc[O_];
#pragma unroll
    for (int o = 0; o < O_; ++o) acc[o] = 0.0f;

    const float* offp = off + (size_t)b * OFFC_ * HW_ + rem;
    const float* modp = mod + (size_t)b * MODC_ * HW_ + rem;

#pragma unroll 1
    for (int g = 0; g < G_; ++g) {
        const float* xg = xt + ((size_t)(b * G_ + g) * HW_) * CG_;
#pragma unroll 1
        for (int k = 0; k < K_; ++k) {
            int ki = k / 3;
            int kj = k - ki * 3;
            float oy = offp[(size_t)(g * 18 + 2 * k) * HW_];
            float ox = offp[(size_t)(g * 18 + 2 * k + 1) * HW_];
            float m  = modp[(size_t)(g * K_ + k) * HW_];

            float py  = oy + (float)(y - 1 + ki);
            float px  = ox + (float)(xx - 1 + kj);
            float y0f = floorf(py), x0f = floorf(px);
            float wy  = py - y0f,   wx  = px - x0f;
            int y0 = (int)y0f, x0i = (int)x0f;
            int y1 = y0 + 1,   x1  = x0i + 1;
            float vy0 = ((unsigned)y0  < (unsigned)H_) ? 1.0f : 0.0f;
            float vy1 = ((unsigned)y1  < (unsigned)H_) ? 1.0f : 0.0f;
            float vx0 = ((unsigned)x0i < (unsigned)W_) ? 1.0f : 0.0f;
            float vx1 = ((unsigned)x1  < (unsigned)W_) ? 1.0f : 0.0f;
            int yc0 = min(max(y0, 0), H_ - 1);
            int yc1 = min(max(y1, 0), H_ - 1);
            int xc0 = min(max(x0i, 0), W_ - 1);
            int xc1 = min(max(x1, 0), W_ - 1);

            float w00 = (1.0f - wy) * (1.0f - wx) * vy0 * vx0 * m;
            float w01 = (1.0f - wy) * wx          * vy0 * vx1 * m;
            float w10 = wy          * (1.0f - wx) * vy1 * vx0 * m;
            float w11 = wy          * wx          * vy1 * vx1 * m;

            const float4* p00 = (const float4*)(xg + (size_t)(yc0 * W_ + xc0) * CG_);
            const float4* p01 = (const float4*)(xg + (size_t)(yc0 * W_ + xc1) * CG_);
            const float4* p10 = (const float4*)(xg + (size_t)(yc1 * W_ + xc0) * CG_);
            const float4* p11 = (const float4*)(xg + (size_t)(yc1 * W_ + xc1) * CG_);

            const float* wp = wt + (size_t)((g * K_ + k) * CG_) * O_;
#pragma unroll 1
            for (int c4 = 0; c4 < 4; ++c4) {
                float4 a = p00[c4], bb = p01[c4], ccc = p10[c4], d = p11[c4];
                float4 v;
                v.x = fmaf(w00, a.x, fmaf(w01, bb.x, fmaf(w10, ccc.x, w11 * d.x)));
                v.y = fmaf(w00, a.y, fmaf(w01, bb.y, fmaf(w10, ccc.y, w11 * d.y)));
                v.z = fmaf(w00, a.z, fmaf(w01, bb.z, fmaf(w10, ccc.z, w11 * d.z)));
                v.w = fmaf(w00, a.w, fmaf(w01, bb.w, fmaf(w10, ccc.w, w11 * d.w)));
#pragma unroll
                for (int cc = 0; cc < 4; ++cc) {
                    float vs = (cc == 0) ? v.x : (cc == 1) ? v.y : (cc == 2) ? v.z : v.w;
                    const float* w = wp + (size_t)(c4 * 4 + cc) * O_;
#pragma unroll
                    for (int o = 0; o < O_; ++o)
                        acc[o] = fmaf(w[o], vs, acc[o]);
                }
            }
        }
    }

    float* op = out + (size_t)b * O_ * HW_ + rem;
#pragma unroll
    for (int o = 0; o < O_; ++o)
        op[(size_t)o * HW_] = acc[o];
}

extern "C" void kernel_launch(void* const* d_in, const int* in_sizes, int n_in,
                              void* d_out, int out_size, void* d_ws, size_t ws_size,
                              hipStream_t stream) {
    const float* warp = (const float*)d_in[0];  // (4,64,160,160)
    const float* omap = (const float*)d_in[1];  // (4,72,160,160)
    const float* wreg = (const float*)d_in[2];  // (64,64,3,3)
    const float* wmod = (const float*)d_in[3];  // (36,64,3,3)
    const float* bmod = (const float*)d_in[4];  // (36,)

    float* out     = (float*)d_out;                     // (4,64,160,160)
    float* out_off = out + (size_t)B_ * O_ * HW_;       // (4,72,160,160)

    float* mod    = (float*)d_ws;                       // 4*36*25600   = 14.75 MB
    float* xt     = mod + (size_t)B_ * MODC_ * HW_;     // 4*64*25600   = 26.2 MB
    float* wt_def = xt + (size_t)B_ * C_ * HW_;         // 36864 floats
    float* wt_mod = wt_def + O_ * C_ * K_;              // 20736 floats

    hipLaunchKernelGGL(k_nhwc, dim3(16 * 100), dim3(256), 0, stream, warp, xt);
    hipLaunchKernelGGL(k_wt, dim3((O_ * C_ * K_ + MODC_ * C_ * K_ + 255) / 256),
                       dim3(256), 0, stream, wreg, wmod, wt_def, wt_mod);
    hipLaunchKernelGGL(k_offsets, dim3((B_ * OFFC_ * HW_ / 4) / 256), dim3(256),
                       0, stream, omap, out_off);
    hipLaunchKernelGGL(k_mod, dim3(B_ * HW_ / 256), dim3(256), 0, stream,
                       xt, wt_mod, bmod, mod);
    hipLaunchKernelGGL(k_deform, dim3(B_ * HW_ / 256), dim3(256), 0, stream,
                       xt, out_off, mod, wt_def, out);
}

// Round 3
// 256.671 us; speedup vs baseline: 7.5957x; 2.3072x over previous
//
#include <hip/hip_runtime.h>

#define B_    4
#define C_    64
#define H_    160
#define W_    160
#define O_    64
#define G_    4
#define K_    9
#define CG_   16
#define MODC_ 36
#define OFFC_ 72
#define HW_   (H_*W_)

typedef __attribute__((ext_vector_type(8))) short short8;   // 8 bf16
typedef __attribute__((ext_vector_type(4))) float f32x4;

#define NCHUNK_ 18           // K=576 contraction, 32 per chunk

__device__ __forceinline__ float sigmoidf(float v) {
    return 1.0f / (1.0f + __expf(-v));
}

// round-to-nearest-even f32 -> bf16 (as short)
__device__ __forceinline__ short f2bf(float f) {
    unsigned u = __float_as_uint(f);
    u += 0x7FFFu + ((u >> 16) & 1u);
    return (short)(u >> 16);
}

// ---------------------------------------------------------------------------
// warp_ref NCHW -> grouped NHWC fp32: xt[((b*4+g)*HW + px)*16 + c]
// ---------------------------------------------------------------------------
__global__ __launch_bounds__(256) void k_nhwc(const float* __restrict__ x,
                                              float* __restrict__ xt) {
    __shared__ float lds[256][17];
    int bg   = blockIdx.x / 100;
    int pix0 = (blockIdx.x % 100) * 256;
    const float* src = x + (size_t)bg * CG_ * HW_ + pix0;
#pragma unroll
    for (int c = 0; c < CG_; ++c)
        lds[threadIdx.x][c] = src[c * HW_ + threadIdx.x];
    __syncthreads();
    float4* dst = (float4*)(xt + ((size_t)bg * HW_ + pix0 + threadIdx.x) * CG_);
#pragma unroll
    for (int q = 0; q < 4; ++q)
        dst[q] = make_float4(lds[threadIdx.x][4 * q + 0],
                             lds[threadIdx.x][4 * q + 1],
                             lds[threadIdx.x][4 * q + 2],
                             lds[threadIdx.x][4 * q + 3]);
}

// ---------------------------------------------------------------------------
// Pack weights into MFMA A-fragment order (bf16).
//  wA_def[cc][mt(4)][lane(64)][8] : A[m=o'][k] for out-conv, contraction
//      idx = cc*32 + quad*8 + j -> gk = idx>>4, c = idx&15, g=gk/9, kk=gk%9
//  wA_mod[cc][mt(3)][lane(64)][8] : A[m=j'][k], idx -> t = idx>>6, c = idx&63
// ---------------------------------------------------------------------------
__global__ __launch_bounds__(256) void k_wt(const float* __restrict__ wreg,
                                            const float* __restrict__ wmod,
                                            short* __restrict__ wA_def,
                                            short* __restrict__ wA_mod) {
    int tid = blockIdx.x * 256 + threadIdx.x;
    if (tid < NCHUNK_ * 4 * 64) {
        int lane = tid & 63;
        int mt   = (tid >> 6) & 3;
        int cc   = tid >> 8;
        int quad = lane >> 4;
        int o    = mt * 16 + (lane & 15);
#pragma unroll
        for (int j = 0; j < 8; ++j) {
            int idx = cc * 32 + quad * 8 + j;
            int gk = idx >> 4, c = idx & 15;
            int g = gk / 9, kk = gk - g * 9;
            wA_def[(size_t)tid * 8 + j] = f2bf(wreg[((o * C_) + g * CG_ + c) * K_ + kk]);
        }
    } else {
        int t2 = tid - NCHUNK_ * 4 * 64;
        if (t2 < NCHUNK_ * 3 * 64) {
            int lane = t2 & 63;
            int mt   = (t2 >> 6) % 3;
            int cc   = t2 / 192;
            int quad = lane >> 4;
            int jch  = mt * 16 + (lane & 15);
#pragma unroll
            for (int j = 0; j < 8; ++j) {
                int idx = cc * 32 + quad * 8 + j;
                int t = idx >> 6, c = idx & 63;
                float v = (jch < MODC_) ? wmod[((jch * C_) + c) * K_ + t] : 0.0f;
                wA_mod[(size_t)t2 * 8 + j] = f2bf(v);
            }
        }
    }
}

// off = 80*sigmoid(offset_map) - 40
__global__ __launch_bounds__(256) void k_offsets(const float* __restrict__ om,
                                                 float* __restrict__ off) {
    int i = blockIdx.x * 256 + threadIdx.x;
    float4 v = ((const float4*)om)[i];
    float4 r;
    r.x = 80.0f * sigmoidf(v.x) - 40.0f;
    r.y = 80.0f * sigmoidf(v.y) - 40.0f;
    r.z = 80.0f * sigmoidf(v.z) - 40.0f;
    r.w = 80.0f * sigmoidf(v.w) - 40.0f;
    ((float4*)off)[i] = r;
}

// ---------------------------------------------------------------------------
// modulator conv via MFMA: D[j(48 pad), px(16)] per wave. 16 px/wave.
// ---------------------------------------------------------------------------
__global__ __launch_bounds__(256) void k_mod(const float* __restrict__ xt,
                                             const short* __restrict__ wA_mod,
                                             const float* __restrict__ bm,
                                             float* __restrict__ mod) {
    int b    = (blockIdx.x & 7) >> 1;                     // XCD -> batch pin
    int tile = ((blockIdx.x >> 3) << 1) + (blockIdx.x & 1); // 0..399
    int wave = threadIdx.x >> 6;
    int lane = threadIdx.x & 63;
    int quad = lane >> 4;
    int p    = tile * 64 + wave * 16 + (lane & 15);       // pixel in [0,25600)
    int y    = p / W_;
    int x    = p - y * W_;

    f32x4 acc0 = {}, acc1 = {}, acc2 = {};

    const short8* wa = (const short8*)wA_mod;

#pragma unroll 1
    for (int cc = 0; cc < NCHUNK_; ++cc) {
        int t  = cc >> 1;
        int dy = t / 3 - 1;
        int dx = t - (t / 3) * 3 - 1;
        int yy = y + dy, xx = x + dx;
        float msk = (((unsigned)yy < (unsigned)H_) && ((unsigned)xx < (unsigned)W_)) ? 1.0f : 0.0f;
        int yc = min(max(yy, 0), H_ - 1);
        int xc = min(max(xx, 0), W_ - 1);
        int ch0 = (cc & 1) * 32 + quad * 8;               // 0..56
        int g   = ch0 >> 4;
        int cl  = ch0 & 15;
        const float4* pp = (const float4*)(xt +
            ((size_t)(b * G_ + g) * HW_ + (size_t)(yc * W_ + xc)) * CG_ + cl);
        float4 v0 = pp[0], v1 = pp[1];
        short8 bfr;
        bfr[0] = f2bf(v0.x * msk); bfr[1] = f2bf(v0.y * msk);
        bfr[2] = f2bf(v0.z * msk); bfr[3] = f2bf(v0.w * msk);
        bfr[4] = f2bf(v1.x * msk); bfr[5] = f2bf(v1.y * msk);
        bfr[6] = f2bf(v1.z * msk); bfr[7] = f2bf(v1.w * msk);

        const short8* w = wa + cc * 192;
        acc0 = __builtin_amdgcn_mfma_f32_16x16x32_bf16(w[lane],        bfr, acc0, 0, 0, 0);
        acc1 = __builtin_amdgcn_mfma_f32_16x16x32_bf16(w[64 + lane],   bfr, acc1, 0, 0, 0);
        acc2 = __builtin_amdgcn_mfma_f32_16x16x32_bf16(w[128 + lane],  bfr, acc2, 0, 0, 0);
    }

    // D: row(j') = quad*4 + reg, col(px) = lane&15
    float* mp = mod + (size_t)b * MODC_ * HW_ + p;
#pragma unroll
    for (int reg = 0; reg < 4; ++reg) {
        int j0 = quad * 4 + reg;
        mp[(size_t)j0 * HW_]        = 2.0f * sigmoidf(acc0[reg] + bm[j0]);
        mp[(size_t)(16 + j0) * HW_] = 2.0f * sigmoidf(acc1[reg] + bm[16 + j0]);
        int j2 = 32 + j0;
        if (j2 < MODC_)
            mp[(size_t)j2 * HW_] = 2.0f * sigmoidf(acc2[reg] + bm[j2]);
    }
}

// ---------------------------------------------------------------------------
// deformable conv via MFMA: D[o(64), px(16)] per wave. Bilinear gather builds
// the B fragment directly in registers (lane -> one pixel, 8 channels, one gk).
// ---------------------------------------------------------------------------
__global__ __launch_bounds__(256) void k_deform(const float* __restrict__ xt,
                                                const float* __restrict__ off,
                                                const float* __restrict__ mod,
                                                const short* __restrict__ wA_def,
                                                float* __restrict__ out) {
    int b    = (blockIdx.x & 7) >> 1;
    int tile = ((blockIdx.x >> 3) << 1) + (blockIdx.x & 1);
    int wave = threadIdx.x >> 6;
    int lane = threadIdx.x & 63;
    int quad = lane >> 4;
    int p    = tile * 64 + wave * 16 + (lane & 15);
    int y    = p / W_;
    int x    = p - y * W_;

    f32x4 acc0 = {}, acc1 = {}, acc2 = {}, acc3 = {};

    const float* offp = off + (size_t)b * OFFC_ * HW_ + p;
    const float* modp = mod + (size_t)b * MODC_ * HW_ + p;
    const short8* wa  = (const short8*)wA_def;
    int cbase = (quad & 1) * 8;

#pragma unroll 1
    for (int cc = 0; cc < NCHUNK_; ++cc) {
        int gk = cc * 2 + (quad >> 1);
        int g  = gk / 9;
        int kk = gk - g * 9;
        int ki = kk / 3;
        int kj = kk - ki * 3;

        float oy = offp[(size_t)(g * 18 + kk * 2) * HW_];
        float ox = offp[(size_t)(g * 18 + kk * 2 + 1) * HW_];
        float fm = modp[(size_t)gk * HW_];

        float py  = oy + (float)(y - 1 + ki);
        float pxf = ox + (float)(x - 1 + kj);
        float y0f = floorf(py), x0f = floorf(pxf);
        float wy  = py - y0f,   wx  = pxf - x0f;
        int y0 = (int)y0f, x0i = (int)x0f;
        int y1 = y0 + 1,   x1  = x0i + 1;
        float vy0 = ((unsigned)y0  < (unsigned)H_) ? 1.0f : 0.0f;
        float vy1 = ((unsigned)y1  < (unsigned)H_) ? 1.0f : 0.0f;
        float vx0 = ((unsigned)x0i < (unsigned)W_) ? 1.0f : 0.0f;
        float vx1 = ((unsigned)x1  < (unsigned)W_) ? 1.0f : 0.0f;
        int yc0 = min(max(y0, 0), H_ - 1);
        int yc1 = min(max(y1, 0), H_ - 1);
        int xc0 = min(max(x0i, 0), W_ - 1);
        int xc1 = min(max(x1, 0), W_ - 1);

        float w00 = (1.0f - wy) * (1.0f - wx) * vy0 * vx0 * fm;
        float w01 = (1.0f - wy) * wx          * vy0 * vx1 * fm;
        float w10 = wy          * (1.0f - wx) * vy1 * vx0 * fm;
        float w11 = wy          * wx          * vy1 * vx1 * fm;

        const float* xg = xt + ((size_t)(b * G_ + g) * HW_) * CG_ + cbase;
        const float4* p00 = (const float4*)(xg + (size_t)(yc0 * W_ + xc0) * CG_);
        const float4* p01 = (const float4*)(xg + (size_t)(yc0 * W_ + xc1) * CG_);
        const float4* p10 = (const float4*)(xg + (size_t)(yc1 * W_ + xc0) * CG_);
        const float4* p11 = (const float4*)(xg + (size_t)(yc1 * W_ + xc1) * CG_);

        float4 a0 = p00[0], a1 = p00[1];
        float4 b0 = p01[0], b1 = p01[1];
        float4 c0 = p10[0], c1 = p10[1];
        float4 d0 = p11[0], d1 = p11[1];

        short8 bfr;
        bfr[0] = f2bf(fmaf(w00, a0.x, fmaf(w01, b0.x, fmaf(w10, c0.x, w11 * d0.x))));
        bfr[1] = f2bf(fmaf(w00, a0.y, fmaf(w01, b0.y, fmaf(w10, c0.y, w11 * d0.y))));
        bfr[2] = f2bf(fmaf(w00, a0.z, fmaf(w01, b0.z, fmaf(w10, c0.z, w11 * d0.z))));
        bfr[3] = f2bf(fmaf(w00, a0.w, fmaf(w01, b0.w, fmaf(w10, c0.w, w11 * d0.w))));
        bfr[4] = f2bf(fmaf(w00, a1.x, fmaf(w01, b1.x, fmaf(w10, c1.x, w11 * d1.x))));
        bfr[5] = f2bf(fmaf(w00, a1.y, fmaf(w01, b1.y, fmaf(w10, c1.y, w11 * d1.y))));
        bfr[6] = f2bf(fmaf(w00, a1.z, fmaf(w01, b1.z, fmaf(w10, c1.z, w11 * d1.z))));
        bfr[7] = f2bf(fmaf(w00, a1.w, fmaf(w01, b1.w, fmaf(w10, c1.w, w11 * d1.w))));

        const short8* w = wa + cc * 256;
        acc0 = __builtin_amdgcn_mfma_f32_16x16x32_bf16(w[lane],        bfr, acc0, 0, 0, 0);
        acc1 = __builtin_amdgcn_mfma_f32_16x16x32_bf16(w[64 + lane],   bfr, acc1, 0, 0, 0);
        acc2 = __builtin_amdgcn_mfma_f32_16x16x32_bf16(w[128 + lane],  bfr, acc2, 0, 0, 0);
        acc3 = __builtin_amdgcn_mfma_f32_16x16x32_bf16(w[192 + lane],  bfr, acc3, 0, 0, 0);
    }

    // D: row(o') = quad*4 + reg, col(px) = lane&15
    float* op = out + (size_t)b * O_ * HW_ + p;
#pragma unroll
    for (int reg = 0; reg < 4; ++reg) {
        int o0 = quad * 4 + reg;
        op[(size_t)o0 * HW_]        = acc0[reg];
        op[(size_t)(16 + o0) * HW_] = acc1[reg];
        op[(size_t)(32 + o0) * HW_] = acc2[reg];
        op[(size_t)(48 + o0) * HW_] = acc3[reg];
    }
}

extern "C" void kernel_launch(void* const* d_in, const int* in_sizes, int n_in,
                              void* d_out, int out_size, void* d_ws, size_t ws_size,
                              hipStream_t stream) {
    const float* warp = (const float*)d_in[0];
    const float* omap = (const float*)d_in[1];
    const float* wreg = (const float*)d_in[2];
    const float* wmod = (const float*)d_in[3];
    const float* bmod = (const float*)d_in[4];

    float* out     = (float*)d_out;                    // (4,64,160,160)
    float* out_off = out + (size_t)B_ * O_ * HW_;      // (4,72,160,160)

    float* mod    = (float*)d_ws;                      // 14.75 MB
    float* xt     = mod + (size_t)B_ * MODC_ * HW_;    // 26.2 MB
    short* wA_def = (short*)(xt + (size_t)B_ * C_ * HW_);   // 18*4*64*8 bf16
    short* wA_mod = wA_def + NCHUNK_ * 4 * 64 * 8;          // 18*3*64*8 bf16

    hipLaunchKernelGGL(k_nhwc, dim3(16 * 100), dim3(256), 0, stream, warp, xt);
    hipLaunchKernelGGL(k_wt, dim3(32), dim3(256), 0, stream,
                       wreg, wmod, wA_def, wA_mod);
    hipLaunchKernelGGL(k_offsets, dim3((B_ * OFFC_ * HW_ / 4) / 256), dim3(256),
                       0, stream, omap, out_off);
    hipLaunchKernelGGL(k_mod, dim3(1600), dim3(256), 0, stream,
                       xt, wA_mod, bmod, mod);
    hipLaunchKernelGGL(k_deform, dim3(1600), dim3(256), 0, stream,
                       xt, out_off, mod, wA_def, out);
}